// Round 10
// baseline (1283.933 us; speedup 1.0000x reference)
//
#include <hip/hip_runtime.h>
#include <math.h>

typedef __bf16 bf16_t;
typedef _Float16 f16_t;
typedef __attribute__((ext_vector_type(8))) __bf16 bf16x8;
typedef __attribute__((ext_vector_type(8))) _Float16 f16x8;
typedef __attribute__((ext_vector_type(4))) float f32x4;

namespace {
constexpr int Bn = 4;
constexpr int Cn = 512;
constexpr int Ln = 4096;   // 64*64
constexpr float kEps = 1e-5f;
constexpr size_t NQK = (size_t)Bn * Ln * Cn;   // 8388608
constexpr size_t CC  = (size_t)Cn * Cn;        // 262144

constexpr size_t FOFF_MEANS = 0;
constexpr size_t FOFF_RSTDS = 2048;
constexpr size_t FOFF_MEANC = 4096;
constexpr size_t FOFF_RSTDC = 6144;
constexpr size_t FOFF_KP    = 8192;            // B*Ln
constexpr size_t FOFF_GSV   = FOFF_KP + 16384;
constexpr size_t FOFF_H1    = FOFF_GSV + 2048;
constexpr size_t FOFF_H2    = FOFF_H1 + 2048;
constexpr size_t FOFF_GAMMA = FOFF_H2 + 2048;
constexpr size_t FOFF_BETA  = FOFF_GAMMA + 2048;
} // namespace

__device__ inline f32x4 mfma_bf(bf16x8 a, bf16x8 b, f32x4 c) {
    return __builtin_amdgcn_mfma_f32_16x16x32_bf16(a, b, c, 0, 0, 0);
}
__device__ inline f32x4 mfma_f16(f16x8 a, f16x8 b, f32x4 c) {
    return __builtin_amdgcn_mfma_f32_16x16x32_f16(a, b, c, 0, 0, 0);
}

__device__ __forceinline__ void gll16(const void* g, void* l) {
    __builtin_amdgcn_global_load_lds((const unsigned int*)g, (unsigned int*)l, 16, 0, 0);
}

__device__ inline unsigned short h2u(f16_t x) {
    union { f16_t h; unsigned short u; } c; c.h = x; return c.u;
}
__device__ inline f16_t u2h(unsigned short x) {
    union { f16_t h; unsigned short u; } c; c.u = x; return c.h;
}

// ---- per-(b,c) mean & rstd over L, ddof=1 ----
__global__ __launch_bounds__(256) void stats_kernel(const float* __restrict__ x,
                                                    float* __restrict__ mean,
                                                    float* __restrict__ rstd) {
    int bc = blockIdx.x;
    const float* row = x + (size_t)bc * Ln;
    float s1 = 0.f, s2 = 0.f;
    for (int i = threadIdx.x; i < Ln; i += 256) {
        float v = row[i];
        s1 += v; s2 += v * v;
    }
    for (int off = 32; off; off >>= 1) {
        s1 += __shfl_down(s1, off);
        s2 += __shfl_down(s2, off);
    }
    __shared__ float a1[4], a2[4];
    int wid = threadIdx.x >> 6;
    if ((threadIdx.x & 63) == 0) { a1[wid] = s1; a2[wid] = s2; }
    __syncthreads();
    if (threadIdx.x == 0) {
        s1 = a1[0] + a1[1] + a1[2] + a1[3];
        s2 = a2[0] + a2[1] + a2[2] + a2[3];
        float m = s1 / Ln;
        float var = (s2 - m * s1) / (Ln - 1);
        mean[bc] = m;
        rstd[bc] = 1.0f / sqrtf(var + kEps);
    }
}

// ---- split 3 weight matrices into bf16 hi/lo ----
__global__ __launch_bounds__(256) void split_w_kernel(const float* __restrict__ w0,
                                                      const float* __restrict__ w1,
                                                      const float* __restrict__ w2,
                                                      bf16_t* __restrict__ wsp) {
    const float* w = (blockIdx.y == 0) ? w0 : (blockIdx.y == 1) ? w1 : w2;
    bf16_t* hi = wsp + (size_t)blockIdx.y * 2 * CC;
    bf16_t* lo = hi + CC;
    size_t i0 = ((size_t)blockIdx.x * 256 + threadIdx.x) * 8;
    float4 a = *(const float4*)(w + i0);
    float4 b = *(const float4*)(w + i0 + 4);
    float vs[8] = {a.x, a.y, a.z, a.w, b.x, b.y, b.z, b.w};
    bf16x8 hv, lv;
#pragma unroll
    for (int i = 0; i < 8; i++) {
        bf16_t h = (bf16_t)vs[i];
        hv[i] = h;
        lv[i] = (bf16_t)(vs[i] - (float)h);
    }
    *(bf16x8*)(hi + i0) = hv;
    *(bf16x8*)(lo + i0) = lv;
}

// ---- transpose+split: X [B][C][L] fp32 -> XT hi/lo [B][L][C] bf16 (opt. mvn) ----
template <bool MVN>
__global__ __launch_bounds__(256) void split_xt_kernel(const float* __restrict__ x,
                                                       const float* __restrict__ mean,
                                                       const float* __restrict__ rstd,
                                                       bf16_t* __restrict__ hi,
                                                       bf16_t* __restrict__ lo) {
    __shared__ bf16_t th[32][40];
    __shared__ bf16_t tl[32][40];
    int b = blockIdx.z, c0 = blockIdx.y * 32, l0 = blockIdx.x * 32;
    const size_t base = (size_t)b * Cn * Ln;
    int lc = threadIdx.x & 31;
    int cr0 = threadIdx.x >> 5;
#pragma unroll
    for (int p = 0; p < 4; p++) {
        int cr = cr0 + p * 8;
        float v = x[base + (size_t)(c0 + cr) * Ln + l0 + lc];
        if constexpr (MVN) {
            v = (v - mean[b * Cn + c0 + cr]) * rstd[b * Cn + c0 + cr];
        }
        bf16_t h = (bf16_t)v;
        th[lc][cr] = h;
        tl[lc][cr] = (bf16_t)(v - (float)h);
    }
    __syncthreads();
    int tt = threadIdx.x & 127;
    int lrow = tt >> 2;
    int c8 = (tt & 3) * 8;
    if (threadIdx.x < 128) {
        *(bf16x8*)(hi + base + (size_t)(l0 + lrow) * Cn + c0 + c8) = *(bf16x8*)&th[lrow][c8];
    } else {
        *(bf16x8*)(lo + base + (size_t)(l0 + lrow) * Cn + c0 + c8) = *(bf16x8*)&tl[lrow][c8];
    }
}

// ---- conv1x1 as split-bf16 MFMA GEMM: out = W(CxC) @ X(CxL) + bias, fp16 out ----
template <int MODE>
__global__ __launch_bounds__(256, 2) void conv_mfma_kernel(
    const bf16_t* __restrict__ Whi, const bf16_t* __restrict__ Wlo,
    const bf16_t* __restrict__ Xhi, const bf16_t* __restrict__ Xlo,
    const float* __restrict__ bias,
    const float* __restrict__ gma, const float* __restrict__ bta,
    f16_t* __restrict__ out0) {
    const int b = blockIdx.z;
    const int o0 = blockIdx.y * 128;
    const int l0 = blockIdx.x * 128;
    const int tid = threadIdx.x;
    const int lane = tid & 63, wid = tid >> 6;
    const int wm = wid & 1, wn = wid >> 1;
    const int lg = lane >> 4, li = lane & 15;
    const size_t bLC = (size_t)b * Ln * Cn;

    __shared__ __align__(16) char smem[66560];

    f32x4 acc[4][4];
#pragma unroll
    for (int i = 0; i < 4; i++)
#pragma unroll
        for (int j = 0; j < 4; j++) acc[i][j] = (f32x4){0.f, 0.f, 0.f, 0.f};

    for (int cc = 0; cc < Cn; cc += 64) {
        __syncthreads();
#pragma unroll
        for (int p = 0; p < 4; p++) {
            int idx = p * 256 + tid;          // 0..1023
            int row = idx >> 3;               // 0..127
            int c8 = (idx & 7) * 8;           // 0..56
            unsigned off = (unsigned)((row * 64 + c8) * 2) ^ (unsigned)((row & 7) << 4);
            *(bf16x8*)(smem + off)         = *(const bf16x8*)(Whi + (size_t)(o0 + row) * Cn + cc + c8);
            *(bf16x8*)(smem + 16384 + off) = *(const bf16x8*)(Wlo + (size_t)(o0 + row) * Cn + cc + c8);
            *(bf16x8*)(smem + 32768 + off) = *(const bf16x8*)(Xhi + bLC + (size_t)(l0 + row) * Cn + cc + c8);
            *(bf16x8*)(smem + 49152 + off) = *(const bf16x8*)(Xlo + bLC + (size_t)(l0 + row) * Cn + cc + c8);
        }
        __syncthreads();
#pragma unroll
        for (int k2 = 0; k2 < 2; k2++) {
            bf16x8 ah[4], al[4], bh[4], bl[4];
#pragma unroll
            for (int f = 0; f < 4; f++) {
                int row = wm * 64 + f * 16 + li;
                unsigned ob = (unsigned)(row * 128 + ((k2 * 64 + lg * 16) ^ ((row & 7) << 4)));
                ah[f] = *(const bf16x8*)(smem + ob);
                al[f] = *(const bf16x8*)(smem + 16384 + ob);
            }
#pragma unroll
            for (int f = 0; f < 4; f++) {
                int row = wn * 64 + f * 16 + li;
                unsigned ob = (unsigned)(row * 128 + ((k2 * 64 + lg * 16) ^ ((row & 7) << 4)));
                bh[f] = *(const bf16x8*)(smem + 32768 + ob);
                bl[f] = *(const bf16x8*)(smem + 49152 + ob);
            }
#pragma unroll
            for (int fm = 0; fm < 4; fm++)
#pragma unroll
                for (int fn = 0; fn < 4; fn++) {
                    acc[fm][fn] = mfma_bf(ah[fm], bh[fn], acc[fm][fn]);
                    acc[fm][fn] = mfma_bf(ah[fm], bl[fn], acc[fm][fn]);
                    acc[fm][fn] = mfma_bf(al[fm], bh[fn], acc[fm][fn]);
                }
        }
    }

    if constexpr (MODE == 0) {
        const size_t bCL = (size_t)b * Cn * Ln;
#pragma unroll
        for (int fm = 0; fm < 4; fm++) {
#pragma unroll
            for (int r = 0; r < 4; r++) {
                int o = o0 + wm * 64 + fm * 16 + lg * 4 + r;
                float bv = bias[o];
#pragma unroll
                for (int fn = 0; fn < 4; fn++) {
                    int l = l0 + wn * 64 + fn * 16 + li;
                    out0[bCL + (size_t)o * Ln + l] = (f16_t)(acc[fm][fn][r] + bv);
                }
            }
        }
    } else {
        __syncthreads();
        unsigned short* ep = (unsigned short*)smem;
#pragma unroll
        for (int fm = 0; fm < 4; fm++) {
#pragma unroll
            for (int r = 0; r < 4; r++) {
                int orow = wm * 64 + fm * 16 + lg * 4 + r;
                int o = o0 + orow;
                float bv = bias[o];
                float gv = 0.f, btv = 0.f;
                if constexpr (MODE == 2) { gv = gma[b * Cn + o]; btv = bta[b * Cn + o]; }
#pragma unroll
                for (int fn = 0; fn < 4; fn++) {
                    int lrow = wn * 64 + fn * 16 + li;
                    float v = acc[fm][fn][r] + bv;
                    if constexpr (MODE == 2) v = v * (1.f + gv) + btv;
                    ep[lrow * 130 + orow] = h2u((f16_t)v);
                }
            }
        }
        __syncthreads();
#pragma unroll
        for (int p = 0; p < 8; p++) {
            int idx = p * 256 + tid;       // 0..2047
            int lrow = idx >> 4;           // 0..127
            int c8 = (idx & 15) * 8;       // 0..120
            f16x8 hv;
#pragma unroll
            for (int u = 0; u < 8; u++) hv[u] = u2h(ep[lrow * 130 + c8 + u]);
            *(f16x8*)(out0 + bLC + (size_t)(l0 + lrow) * Cn + o0 + c8) = hv;
        }
    }
}

// ---- key_pool[b,l] = sum_c vsp_w[c]*mvn(style)[b,c,l] + vsp_b ----
__global__ __launch_bounds__(256) void keypool_kernel(const float* __restrict__ style,
                                                      const float* __restrict__ vsp_w,
                                                      const float* __restrict__ vsp_b,
                                                      const float* __restrict__ mean_s,
                                                      const float* __restrict__ rstd_s,
                                                      float* __restrict__ kp) {
    int b = blockIdx.y;
    int l = blockIdx.x * 256 + threadIdx.x;
    const size_t bCL = (size_t)b * Cn * Ln;
    float acc = 0.f;
    for (int c = 0; c < Cn; c++) {
        float v = style[bCL + (size_t)c * Ln + l];
        acc += vsp_w[c] * (v - mean_s[b * Cn + c]) * rstd_s[b * Cn + c];
    }
    kp[b * Ln + l] = acc + vsp_b[0];
}

// ---- softmax over L per b, in place ----
__global__ __launch_bounds__(1024) void softmax_kp_kernel(float* __restrict__ kp) {
    int b = blockIdx.x;
    float* p = kp + (size_t)b * Ln;
    int tid = threadIdx.x;
    float v[4];
    float m = -3e38f;
#pragma unroll
    for (int j = 0; j < 4; j++) { v[j] = p[tid + 1024 * j]; m = fmaxf(m, v[j]); }
    __shared__ float red[16];
    for (int off = 32; off; off >>= 1) m = fmaxf(m, __shfl_down(m, off));
    if ((tid & 63) == 0) red[tid >> 6] = m;
    __syncthreads();
    if (tid == 0) {
        float mm = red[0];
        for (int i = 1; i < 16; i++) mm = fmaxf(mm, red[i]);
        red[0] = mm;
    }
    __syncthreads();
    m = red[0];
    __syncthreads();
    float e[4]; float s = 0.f;
#pragma unroll
    for (int j = 0; j < 4; j++) { e[j] = __expf(v[j] - m); s += e[j]; }
    for (int off = 32; off; off >>= 1) s += __shfl_down(s, off);
    if ((tid & 63) == 0) red[tid >> 6] = s;
    __syncthreads();
    if (tid == 0) {
        float ss = 0.f;
        for (int i = 0; i < 16; i++) ss += red[i];
        red[0] = ss;
    }
    __syncthreads();
    float inv = 1.0f / red[0];
#pragma unroll
    for (int j = 0; j < 4; j++) p[tid + 1024 * j] = e[j] * inv;
}

// ---- gsv[b,c] = sum_l Vf[b,c,l]*w[b,l] ----
__global__ __launch_bounds__(256) void gsv_kernel(const f16_t* __restrict__ Vf,
                                                  const float* __restrict__ w,
                                                  float* __restrict__ gsv) {
    int c = blockIdx.x, b = blockIdx.y;
    int tid = threadIdx.x;
    const f16_t* vp = Vf + ((size_t)b * Cn + c) * Ln;
    const float* wp = w + (size_t)b * Ln;
    float acc = 0.f;
    for (int base = tid * 8; base < Ln; base += 2048) {
        f16x8 v = *(const f16x8*)(vp + base);
        float4 w0 = *(const float4*)(wp + base);
        float4 w1 = *(const float4*)(wp + base + 4);
        acc += (float)v[0] * w0.x + (float)v[1] * w0.y + (float)v[2] * w0.z + (float)v[3] * w0.w;
        acc += (float)v[4] * w1.x + (float)v[5] * w1.y + (float)v[6] * w1.z + (float)v[7] * w1.w;
    }
    for (int off = 32; off; off >>= 1) acc += __shfl_down(acc, off);
    __shared__ float red[4];
    if ((tid & 63) == 0) red[tid >> 6] = acc;
    __syncthreads();
    if (tid == 0) gsv[(size_t)b * Cn + c] = red[0] + red[1] + red[2] + red[3];
}

// ---- MLP stage 1 ----
__global__ __launch_bounds__(256) void mlp_hidden_kernel(const float* __restrict__ gsv,
                                                         const float* __restrict__ w1a, const float* __restrict__ b1a,
                                                         const float* __restrict__ w1b, const float* __restrict__ b1b,
                                                         float* __restrict__ h1, float* __restrict__ h2) {
    int idx = blockIdx.x * 256 + threadIdx.x;
    int b = idx / Cn, c = idx % Cn;
    float a1 = b1a[c], a2 = b1b[c];
    for (int k = 0; k < Cn; k++) {
        float g = gsv[b * Cn + k];
        a1 += w1a[(size_t)c * Cn + k] * g;
        a2 += w1b[(size_t)c * Cn + k] * g;
    }
    h1[idx] = fmaxf(a1, 0.f);
    h2[idx] = fmaxf(a2, 0.f);
}

// ---- MLP stage 2 ----
__global__ __launch_bounds__(256) void mlp_out_kernel(const float* __restrict__ h1, const float* __restrict__ h2,
                                                      const float* __restrict__ w2a, const float* __restrict__ b2a,
                                                      const float* __restrict__ w2b, const float* __restrict__ b2b,
                                                      float* __restrict__ gamma, float* __restrict__ beta) {
    int idx = blockIdx.x * 256 + threadIdx.x;
    int b = idx / Cn, c = idx % Cn;
    float a1 = b2a[c], a2 = b2b[c];
    for (int k = 0; k < Cn; k++) {
        a1 += w2a[(size_t)c * Cn + k] * h1[b * Cn + k];
        a2 += w2b[(size_t)c * Cn + k] * h2[b * Cn + k];
    }
    gamma[idx] = a1;
    beta[idx] = a2;
}

// ---- fp16 MFMA flash attention: BQ=32, BK=64, 4 waves, Q in registers,
//      4-buffer async K ring (depth 3), V 2-deep register prefetch,
//      XCD-chunked block swizzle ----
__global__ __launch_bounds__(256, 2) void flash_kernel(
    const f16_t* __restrict__ Qf, const f16_t* __restrict__ Kf,
    const f16_t* __restrict__ Vf, float* __restrict__ Ot) {
    // XCD-chunked swizzle: 512 blocks, 8 XCDs -> 64 contiguous wgids per XCD
    const int bid = blockIdx.x;
    const int wgid = (bid & 7) * 64 + (bid >> 3);
    const int b = wgid >> 7;
    const int q0 = (wgid & 127) * 32;

    const int tid = threadIdx.x;
    const int lane = tid & 63;
    const int wn = tid >> 6;                 // 0..3: key group (energy) / c group (PV)
    const int lg = lane >> 4, li = lane & 15;

    __shared__ __align__(16) f16_t kbuf[4 * 4096];   // 32KB: 4 bufs x [64key x 64c], pitch 128B, swz (key&7)<<4
    __shared__ __align__(16) f16_t pb_s[32 * 64];    // 4KB, pitch 128B, swz (q&7)<<4
    __shared__ float smx[4][32];
    __shared__ float sml[4][32];

    const size_t qbase = ((size_t)b * Ln + q0) * Cn;
    const size_t kbase = (size_t)b * Ln * Cn;
    const size_t vbase = (size_t)b * Cn * Ln;

    // ---- Q into registers: qf[m][cs][k2], lives across all 64 tiles ----
    f16x8 qf[2][8][2];
#pragma unroll
    for (int m = 0; m < 2; m++)
#pragma unroll
        for (int cs = 0; cs < 8; cs++)
#pragma unroll
            for (int k2 = 0; k2 < 2; k2++)
                qf[m][cs][k2] = *(const f16x8*)(Qf + qbase + (size_t)(m * 16 + li) * Cn +
                                                cs * 64 + k2 * 32 + lg * 8);

    // K chunk staging: chunk = [64 keys][64 c] fp16 = 8KB, 2 gll/thread
    auto stageK = [&](int ktA, int cs, int bufi) {
#pragma unroll
        for (int i = 0; i < 2; i++) {
            int idx = i * 256 + tid;              // 0..511
            int key = idx >> 3, slot = idx & 7;
            int sp = slot ^ (key & 7);
            gll16(Kf + kbase + (size_t)(ktA + key) * Cn + cs * 64 + sp * 8,
                  kbuf + (size_t)bufi * 4096 + (size_t)idx * 8);
        }
    };

    // prologue: chunks 0,1,2 of kt=0 into bufs 0,1,2
    stageK(0, 0, 0);
    stageK(0, 1, 1);
    stageK(0, 2, 2);

    f32x4 o[2][8];
#pragma unroll
    for (int m = 0; m < 2; m++)
#pragma unroll
        for (int j = 0; j < 8; j++) o[m][j] = (f32x4){0.f, 0.f, 0.f, 0.f};
    float m_run[2][4], l_run[2][4];
#pragma unroll
    for (int m = 0; m < 2; m++)
#pragma unroll
        for (int r = 0; r < 4; r++) { m_run[m][r] = -1e30f; l_run[m][r] = 0.f; }

    const int key = wn * 16 + li;
    const unsigned kswz = (unsigned)((key & 7) << 4);

    for (int tile = 0; tile < 64; tile++) {
        const int kt = tile * 64;
        f32x4 e[2];
#pragma unroll
        for (int m = 0; m < 2; m++) e[m] = (f32x4){0.f, 0.f, 0.f, 0.f};

        // ================= energy: 8 chunks of 64c, 4-buffer ring depth 3 =================
#pragma unroll
        for (int cs = 0; cs < 8; cs++) {
            const int cur = tile * 8 + cs;
            // chunk cur ready when <= 2 newer chunks (4 glls) outstanding
            if (cur < 510) {
                asm volatile("s_waitcnt vmcnt(4)" ::: "memory");
            } else if (cur == 510) {
                asm volatile("s_waitcnt vmcnt(2)" ::: "memory");
            } else {
                asm volatile("s_waitcnt vmcnt(0)" ::: "memory");
            }
            asm volatile("s_barrier" ::: "memory");
            {
                int c3 = cur + 3;
                if (c3 < 512) stageK((c3 >> 3) << 6, c3 & 7, c3 & 3);
            }
            const char* kb = (const char*)kbuf + (cur & 3) * 8192;
#pragma unroll
            for (int k2 = 0; k2 < 2; k2++) {
                f16x8 bk = *(const f16x8*)(kb + key * 128 + ((k2 * 64 + lg * 16) ^ kswz));
                __builtin_amdgcn_s_setprio(1);
#pragma unroll
                for (int m = 0; m < 2; m++)
                    e[m] = mfma_f16(qf[m][cs][k2], bk, e[m]);
                __builtin_amdgcn_s_setprio(0);
            }
        }

        // ---- issue V prefetch for steps 0,1 NOW (softmax covers the latency) ----
        f16x8 va[2], vb[2];
        {
            const f16_t* vp0 = Vf + vbase + (size_t)(0 * 4 + wn) * 16 * Ln + (size_t)li * Ln + kt + lg * 8;
            va[0] = *(const f16x8*)(vp0);
            vb[0] = *(const f16x8*)(vp0 + 32);
            const f16_t* vp1 = Vf + vbase + (size_t)(1 * 4 + wn) * 16 * Ln + (size_t)li * Ln + kt + lg * 8;
            va[1] = *(const f16x8*)(vp1);
            vb[1] = *(const f16x8*)(vp1 + 32);
        }

        // ================= online softmax =================
        float tmax[2][4];
#pragma unroll
        for (int m = 0; m < 2; m++)
#pragma unroll
            for (int r = 0; r < 4; r++) tmax[m][r] = e[m][r];
#pragma unroll
        for (int d = 1; d < 16; d <<= 1)
#pragma unroll
            for (int m = 0; m < 2; m++)
#pragma unroll
                for (int r = 0; r < 4; r++) tmax[m][r] = fmaxf(tmax[m][r], __shfl_xor(tmax[m][r], d));
        if (li == 0) {
#pragma unroll
            for (int m = 0; m < 2; m++)
#pragma unroll
                for (int r = 0; r < 4; r++) smx[wn][m * 16 + lg * 4 + r] = tmax[m][r];
        }
        asm volatile("s_waitcnt lgkmcnt(0)\n\ts_barrier" ::: "memory");
        float scv[2][4];
        bool anyresc = false;
#pragma unroll
        for (int m = 0; m < 2; m++)
#pragma unroll
            for (int r = 0; r < 4; r++) {
                int row = m * 16 + lg * 4 + r;
                float tm = fmaxf(fmaxf(smx[0][row], smx[1][row]), fmaxf(smx[2][row], smx[3][row]));
                float mnew = fmaxf(m_run[m][r], tm);
                scv[m][r] = __expf(m_run[m][r] - mnew);
                anyresc |= (mnew > m_run[m][r]);
                m_run[m][r] = mnew;
            }
        float pv[2][4], rsum[2][4];
#pragma unroll
        for (int m = 0; m < 2; m++)
#pragma unroll
            for (int r = 0; r < 4; r++) {
                float pe = __expf(e[m][r] - m_run[m][r]);
                pv[m][r] = pe;
                rsum[m][r] = pe;
            }
#pragma unroll
        for (int d = 1; d < 16; d <<= 1)
#pragma unroll
            for (int m = 0; m < 2; m++)
#pragma unroll
                for (int r = 0; r < 4; r++) rsum[m][r] += __shfl_xor(rsum[m][r], d);
        if (li == 0) {
#pragma unroll
            for (int m = 0; m < 2; m++)
#pragma unroll
                for (int r = 0; r < 4; r++) sml[wn][m * 16 + lg * 4 + r] = rsum[m][r];
        }
        // write P fp16 to LDS (swizzled for b128 A-frag reads)
#pragma unroll
        for (int m = 0; m < 2; m++)
#pragma unroll
            for (int r = 0; r < 4; r++) {
                int qrow = m * 16 + lg * 4 + r;
                unsigned boff = (unsigned)(qrow * 128 + ((2 * key) ^ ((qrow & 7) << 4)));
                *(f16_t*)((char*)pb_s + boff) = (f16_t)pv[m][r];
            }
        // rescale O (skip when all scv == 1: exact identity)
        if (__any((int)anyresc)) {
#pragma unroll
            for (int m = 0; m < 2; m++)
#pragma unroll
                for (int j = 0; j < 8; j++)
#pragma unroll
                    for (int r = 0; r < 4; r++) o[m][j][r] *= scv[m][r];
        }
        asm volatile("s_waitcnt lgkmcnt(0)\n\ts_barrier" ::: "memory");
#pragma unroll
        for (int m = 0; m < 2; m++)
#pragma unroll
            for (int r = 0; r < 4; r++) {
                int row = m * 16 + lg * 4 + r;
                l_run[m][r] = l_run[m][r] * scv[m][r] + sml[0][row] + sml[1][row] + sml[2][row] + sml[3][row];
            }

        // ================= PV: P from LDS (b128), V direct from L2, 2-deep prefetch ====
        f16x8 pa[2][2];
#pragma unroll
        for (int m = 0; m < 2; m++)
#pragma unroll
            for (int k2 = 0; k2 < 2; k2++) {
                int qrow = m * 16 + li;
                pa[m][k2] = *(const f16x8*)((const char*)pb_s + qrow * 128 +
                              ((k2 * 64 + lg * 16) ^ ((qrow & 7) << 4)));
            }
#pragma unroll
        for (int n = 0; n < 8; n++) {
            const int slot = n & 1;
            f16x8 c0 = va[slot], c1 = vb[slot];
            if (n + 2 < 8) {
                int cg = (n + 2) * 4 + wn;
                const f16_t* vp = Vf + vbase + (size_t)(cg * 16 + li) * Ln + kt + lg * 8;
                va[slot] = *(const f16x8*)(vp);
                vb[slot] = *(const f16x8*)(vp + 32);
            }
            __builtin_amdgcn_s_setprio(1);
#pragma unroll
            for (int m = 0; m < 2; m++) {
                o[m][n] = mfma_f16(pa[m][0], c0, o[m][n]);
                o[m][n] = mfma_f16(pa[m][1], c1, o[m][n]);
            }
            __builtin_amdgcn_s_setprio(0);
        }
    }

    // ================= epilogue: O^T -> d_out [B][C][L], float4 along L =================
#pragma unroll
    for (int m = 0; m < 2; m++)
#pragma unroll
        for (int r = 0; r < 4; r++) l_run[m][r] = 1.f / l_run[m][r];
#pragma unroll
    for (int m = 0; m < 2; m++)
#pragma unroll
        for (int n = 0; n < 8; n++) {
            int c = (n * 4 + wn) * 16 + li;
            int qg = q0 + m * 16 + lg * 4;
            float4 ov;
            ov.x = o[m][n][0] * l_run[m][0];
            ov.y = o[m][n][1] * l_run[m][1];
            ov.z = o[m][n][2] * l_run[m][2];
            ov.w = o[m][n][3] * l_run[m][3];
            *(float4*)(Ot + vbase + (size_t)c * Ln + qg) = ov;
        }
}

// ---- final: out[b,c,l] = mvn(content)[b,c,l] + out[b,c,l]  (in place) ----
__global__ __launch_bounds__(256) void final_kernel(const float* __restrict__ content,
                                                    const float* __restrict__ mean_c,
                                                    const float* __restrict__ rstd_c,
                                                    float* __restrict__ out) {
    size_t gid = (size_t)blockIdx.x * 256 + threadIdx.x;
    size_t linear = gid * 4;
    int ch = (int)(linear / Ln);
    float m = mean_c[ch], rs = rstd_c[ch];
    float4 cv = *(const float4*)(content + linear);
    float4 ov = *(const float4*)(out + linear);
    ov.x += (cv.x - m) * rs;
    ov.y += (cv.y - m) * rs;
    ov.z += (cv.z - m) * rs;
    ov.w += (cv.w - m) * rs;
    *(float4*)(out + linear) = ov;
}

extern "C" void kernel_launch(void* const* d_in, const int* in_sizes, int n_in,
                              void* d_out, int out_size, void* d_ws, size_t ws_size,
                              hipStream_t stream) {
    const float* content = (const float*)d_in[0];
    const float* style   = (const float*)d_in[1];
    const float* v_w   = (const float*)d_in[2];
    const float* v_b   = (const float*)d_in[3];
    const float* vsp_w = (const float*)d_in[4];
    const float* vsp_b = (const float*)d_in[5];
    const float* k_w   = (const float*)d_in[6];
    const float* k_b   = (const float*)d_in[7];
    const float* qg_w  = (const float*)d_in[8];
    const float* qg_b  = (const float*)d_in[9];
    const float* g1_w1 = (const float*)d_in[10];
    const float* g1_b1 = (const float*)d_in[11];
    const float* g1_w2 = (const float*)d_in[12];
    const float* g1_b2 = (const float*)d_in[13];
    const float* g2_w1 = (const float*)d_in[14];
    const float* g2_b1 = (const float*)d_in[15];
    const float* g2_w2 = (const float*)d_in[16];
    const float* g2_b2 = (const float*)d_in[17];

    f16_t* wsh = (f16_t*)d_ws;
    f16_t* Qf = wsh;
    f16_t* Kf = wsh + NQK;
    f16_t* Vf = wsh + 2 * NQK;
    bf16_t* wsp = (bf16_t*)(wsh + 3 * NQK);
    bf16_t* Wv_hi = wsp;            bf16_t* Wv_lo = wsp + CC;
    bf16_t* Wk_hi = wsp + 2 * CC;   bf16_t* Wk_lo = wsp + 3 * CC;
    bf16_t* Wq_hi = wsp + 4 * CC;   bf16_t* Wq_lo = wsp + 5 * CC;

    float* wsf = (float*)(wsp + 6 * CC);
    float* mean_s = wsf + FOFF_MEANS;
    float* rstd_s = wsf + FOFF_RSTDS;
    float* mean_c = wsf + FOFF_MEANC;
    float* rstd_c = wsf + FOFF_RSTDC;
    float* kp     = wsf + FOFF_KP;
    float* gsv    = wsf + FOFF_GSV;
    float* h1     = wsf + FOFF_H1;
    float* h2     = wsf + FOFF_H2;
    float* gamma  = wsf + FOFF_GAMMA;
    float* beta   = wsf + FOFF_BETA;

    // d_out doubles as scratch for transposed input splits
    bf16_t* XThi = (bf16_t*)d_out;
    bf16_t* XTlo = XThi + NQK;
    float* outF  = (float*)d_out;

    // 1) stats
    stats_kernel<<<dim3(Bn * Cn), 256, 0, stream>>>(style, mean_s, rstd_s);
    stats_kernel<<<dim3(Bn * Cn), 256, 0, stream>>>(content, mean_c, rstd_c);

    // 2) weight splits + style transpose-split (into d_out)
    split_w_kernel<<<dim3(CC / 2048, 3), 256, 0, stream>>>(v_w, k_w, qg_w, wsp);
    split_xt_kernel<false><<<dim3(Ln / 32, Cn / 32, Bn), 256, 0, stream>>>(style, nullptr, nullptr, XThi, XTlo);

    // 3) V conv -> fp16 [B][C][L]
    dim3 cgrid(Ln / 128, Cn / 128, Bn);
    conv_mfma_kernel<0><<<cgrid, 256, 0, stream>>>(Wv_hi, Wv_lo, XThi, XTlo, v_b, nullptr, nullptr, Vf);

    // 4) key_pool + softmax + gsv + MLPs -> gamma, beta
    keypool_kernel<<<dim3(Ln / 256, Bn), 256, 0, stream>>>(style, vsp_w, vsp_b, mean_s, rstd_s, kp);
    softmax_kp_kernel<<<dim3(Bn), 1024, 0, stream>>>(kp);
    gsv_kernel<<<dim3(Cn, Bn), 256, 0, stream>>>(Vf, kp, gsv);
    mlp_hidden_kernel<<<dim3(Bn * Cn / 256), 256, 0, stream>>>(gsv, g1_w1, g1_b1, g2_w1, g2_b1, h1, h2);
    mlp_out_kernel<<<dim3(Bn * Cn / 256), 256, 0, stream>>>(h1, h2, g1_w2, g1_b2, g2_w2, g2_b2, gamma, beta);

    // 5) K conv -> fp16 [B][L][C]
    conv_mfma_kernel<1><<<cgrid, 256, 0, stream>>>(Wk_hi, Wk_lo, XThi, XTlo, k_b, nullptr, nullptr, Kf);

    // 6) content mvn transpose-split (overwrites style split), then Q conv (gamma/beta fused)
    split_xt_kernel<true><<<dim3(Ln / 32, Cn / 32, Bn), 256, 0, stream>>>(content, mean_c, rstd_c, XThi, XTlo);
    conv_mfma_kernel<2><<<cgrid, 256, 0, stream>>>(Wq_hi, Wq_lo, XThi, XTlo, qg_b, gamma, beta, Qf);

    // 7) flash attention -> O^T into d_out  (flat 512-block grid, XCD-swizzled)
    flash_kernel<<<dim3((Ln / 32) * Bn), 256, 0, stream>>>(Qf, Kf, Vf, outF);

    // 8) final: add mvn(content) in place
    final_kernel<<<dim3((Bn * Cn * (Ln / 4)) / 256), 256, 0, stream>>>(content, mean_c, rstd_c, outF);
}

// Round 11
// 709.010 us; speedup vs baseline: 1.8109x; 1.8109x over previous
//
#include <hip/hip_runtime.h>
#include <math.h>

typedef __bf16 bf16_t;
typedef _Float16 f16_t;
typedef __attribute__((ext_vector_type(8))) __bf16 bf16x8;
typedef __attribute__((ext_vector_type(8))) _Float16 f16x8;
typedef __attribute__((ext_vector_type(4))) float f32x4;

namespace {
constexpr int Bn = 4;
constexpr int Cn = 512;
constexpr int Ln = 4096;   // 64*64
constexpr float kEps = 1e-5f;
constexpr size_t NQK = (size_t)Bn * Ln * Cn;   // 8388608
constexpr size_t CC  = (size_t)Cn * Cn;        // 262144

constexpr size_t FOFF_MEANS = 0;
constexpr size_t FOFF_RSTDS = 2048;
constexpr size_t FOFF_MEANC = 4096;
constexpr size_t FOFF_RSTDC = 6144;
constexpr size_t FOFF_KP    = 8192;            // B*Ln
constexpr size_t FOFF_GSV   = FOFF_KP + 16384;
constexpr size_t FOFF_H1    = FOFF_GSV + 2048;
constexpr size_t FOFF_H2    = FOFF_H1 + 2048;
constexpr size_t FOFF_GAMMA = FOFF_H2 + 2048;
constexpr size_t FOFF_BETA  = FOFF_GAMMA + 2048;
} // namespace

__device__ inline f32x4 mfma_bf(bf16x8 a, bf16x8 b, f32x4 c) {
    return __builtin_amdgcn_mfma_f32_16x16x32_bf16(a, b, c, 0, 0, 0);
}
__device__ inline f32x4 mfma_f16(f16x8 a, f16x8 b, f32x4 c) {
    return __builtin_amdgcn_mfma_f32_16x16x32_f16(a, b, c, 0, 0, 0);
}

__device__ __forceinline__ void gll16(const void* g, void* l) {
    __builtin_amdgcn_global_load_lds((const unsigned int*)g, (unsigned int*)l, 16, 0, 0);
}

__device__ inline unsigned short h2u(f16_t x) {
    union { f16_t h; unsigned short u; } c; c.h = x; return c.u;
}
__device__ inline f16_t u2h(unsigned short x) {
    union { f16_t h; unsigned short u; } c; c.u = x; return c.h;
}

// ---- per-(b,c) mean & rstd over L, ddof=1 ----
__global__ __launch_bounds__(256) void stats_kernel(const float* __restrict__ x,
                                                    float* __restrict__ mean,
                                                    float* __restrict__ rstd) {
    int bc = blockIdx.x;
    const float* row = x + (size_t)bc * Ln;
    float s1 = 0.f, s2 = 0.f;
    for (int i = threadIdx.x; i < Ln; i += 256) {
        float v = row[i];
        s1 += v; s2 += v * v;
    }
    for (int off = 32; off; off >>= 1) {
        s1 += __shfl_down(s1, off);
        s2 += __shfl_down(s2, off);
    }
    __shared__ float a1[4], a2[4];
    int wid = threadIdx.x >> 6;
    if ((threadIdx.x & 63) == 0) { a1[wid] = s1; a2[wid] = s2; }
    __syncthreads();
    if (threadIdx.x == 0) {
        s1 = a1[0] + a1[1] + a1[2] + a1[3];
        s2 = a2[0] + a2[1] + a2[2] + a2[3];
        float m = s1 / Ln;
        float var = (s2 - m * s1) / (Ln - 1);
        mean[bc] = m;
        rstd[bc] = 1.0f / sqrtf(var + kEps);
    }
}

// ---- split 3 weight matrices into bf16 hi/lo ----
__global__ __launch_bounds__(256) void split_w_kernel(const float* __restrict__ w0,
                                                      const float* __restrict__ w1,
                                                      const float* __restrict__ w2,
                                                      bf16_t* __restrict__ wsp) {
    const float* w = (blockIdx.y == 0) ? w0 : (blockIdx.y == 1) ? w1 : w2;
    bf16_t* hi = wsp + (size_t)blockIdx.y * 2 * CC;
    bf16_t* lo = hi + CC;
    size_t i0 = ((size_t)blockIdx.x * 256 + threadIdx.x) * 8;
    float4 a = *(const float4*)(w + i0);
    float4 b = *(const float4*)(w + i0 + 4);
    float vs[8] = {a.x, a.y, a.z, a.w, b.x, b.y, b.z, b.w};
    bf16x8 hv, lv;
#pragma unroll
    for (int i = 0; i < 8; i++) {
        bf16_t h = (bf16_t)vs[i];
        hv[i] = h;
        lv[i] = (bf16_t)(vs[i] - (float)h);
    }
    *(bf16x8*)(hi + i0) = hv;
    *(bf16x8*)(lo + i0) = lv;
}

// ---- transpose+split: X [B][C][L] fp32 -> XT hi/lo [B][L][C] bf16 (opt. mvn) ----
template <bool MVN>
__global__ __launch_bounds__(256) void split_xt_kernel(const float* __restrict__ x,
                                                       const float* __restrict__ mean,
                                                       const float* __restrict__ rstd,
                                                       bf16_t* __restrict__ hi,
                                                       bf16_t* __restrict__ lo) {
    __shared__ bf16_t th[32][40];
    __shared__ bf16_t tl[32][40];
    int b = blockIdx.z, c0 = blockIdx.y * 32, l0 = blockIdx.x * 32;
    const size_t base = (size_t)b * Cn * Ln;
    int lc = threadIdx.x & 31;
    int cr0 = threadIdx.x >> 5;
#pragma unroll
    for (int p = 0; p < 4; p++) {
        int cr = cr0 + p * 8;
        float v = x[base + (size_t)(c0 + cr) * Ln + l0 + lc];
        if constexpr (MVN) {
            v = (v - mean[b * Cn + c0 + cr]) * rstd[b * Cn + c0 + cr];
        }
        bf16_t h = (bf16_t)v;
        th[lc][cr] = h;
        tl[lc][cr] = (bf16_t)(v - (float)h);
    }
    __syncthreads();
    int tt = threadIdx.x & 127;
    int lrow = tt >> 2;
    int c8 = (tt & 3) * 8;
    if (threadIdx.x < 128) {
        *(bf16x8*)(hi + base + (size_t)(l0 + lrow) * Cn + c0 + c8) = *(bf16x8*)&th[lrow][c8];
    } else {
        *(bf16x8*)(lo + base + (size_t)(l0 + lrow) * Cn + c0 + c8) = *(bf16x8*)&tl[lrow][c8];
    }
}

// ---- conv1x1 as split-bf16 MFMA GEMM: out = W(CxC) @ X(CxL) + bias, fp16 out ----
template <int MODE>
__global__ __launch_bounds__(256, 2) void conv_mfma_kernel(
    const bf16_t* __restrict__ Whi, const bf16_t* __restrict__ Wlo,
    const bf16_t* __restrict__ Xhi, const bf16_t* __restrict__ Xlo,
    const float* __restrict__ bias,
    const float* __restrict__ gma, const float* __restrict__ bta,
    f16_t* __restrict__ out0) {
    const int b = blockIdx.z;
    const int o0 = blockIdx.y * 128;
    const int l0 = blockIdx.x * 128;
    const int tid = threadIdx.x;
    const int lane = tid & 63, wid = tid >> 6;
    const int wm = wid & 1, wn = wid >> 1;
    const int lg = lane >> 4, li = lane & 15;
    const size_t bLC = (size_t)b * Ln * Cn;

    __shared__ __align__(16) char smem[66560];

    f32x4 acc[4][4];
#pragma unroll
    for (int i = 0; i < 4; i++)
#pragma unroll
        for (int j = 0; j < 4; j++) acc[i][j] = (f32x4){0.f, 0.f, 0.f, 0.f};

    for (int cc = 0; cc < Cn; cc += 64) {
        __syncthreads();
#pragma unroll
        for (int p = 0; p < 4; p++) {
            int idx = p * 256 + tid;          // 0..1023
            int row = idx >> 3;               // 0..127
            int c8 = (idx & 7) * 8;           // 0..56
            unsigned off = (unsigned)((row * 64 + c8) * 2) ^ (unsigned)((row & 7) << 4);
            *(bf16x8*)(smem + off)         = *(const bf16x8*)(Whi + (size_t)(o0 + row) * Cn + cc + c8);
            *(bf16x8*)(smem + 16384 + off) = *(const bf16x8*)(Wlo + (size_t)(o0 + row) * Cn + cc + c8);
            *(bf16x8*)(smem + 32768 + off) = *(const bf16x8*)(Xhi + bLC + (size_t)(l0 + row) * Cn + cc + c8);
            *(bf16x8*)(smem + 49152 + off) = *(const bf16x8*)(Xlo + bLC + (size_t)(l0 + row) * Cn + cc + c8);
        }
        __syncthreads();
#pragma unroll
        for (int k2 = 0; k2 < 2; k2++) {
            bf16x8 ah[4], al[4], bh[4], bl[4];
#pragma unroll
            for (int f = 0; f < 4; f++) {
                int row = wm * 64 + f * 16 + li;
                unsigned ob = (unsigned)(row * 128 + ((k2 * 64 + lg * 16) ^ ((row & 7) << 4)));
                ah[f] = *(const bf16x8*)(smem + ob);
                al[f] = *(const bf16x8*)(smem + 16384 + ob);
            }
#pragma unroll
            for (int f = 0; f < 4; f++) {
                int row = wn * 64 + f * 16 + li;
                unsigned ob = (unsigned)(row * 128 + ((k2 * 64 + lg * 16) ^ ((row & 7) << 4)));
                bh[f] = *(const bf16x8*)(smem + 32768 + ob);
                bl[f] = *(const bf16x8*)(smem + 49152 + ob);
            }
#pragma unroll
            for (int fm = 0; fm < 4; fm++)
#pragma unroll
                for (int fn = 0; fn < 4; fn++) {
                    acc[fm][fn] = mfma_bf(ah[fm], bh[fn], acc[fm][fn]);
                    acc[fm][fn] = mfma_bf(ah[fm], bl[fn], acc[fm][fn]);
                    acc[fm][fn] = mfma_bf(al[fm], bh[fn], acc[fm][fn]);
                }
        }
    }

    if constexpr (MODE == 0) {
        const size_t bCL = (size_t)b * Cn * Ln;
#pragma unroll
        for (int fm = 0; fm < 4; fm++) {
#pragma unroll
            for (int r = 0; r < 4; r++) {
                int o = o0 + wm * 64 + fm * 16 + lg * 4 + r;
                float bv = bias[o];
#pragma unroll
                for (int fn = 0; fn < 4; fn++) {
                    int l = l0 + wn * 64 + fn * 16 + li;
                    out0[bCL + (size_t)o * Ln + l] = (f16_t)(acc[fm][fn][r] + bv);
                }
            }
        }
    } else {
        __syncthreads();
        unsigned short* ep = (unsigned short*)smem;
#pragma unroll
        for (int fm = 0; fm < 4; fm++) {
#pragma unroll
            for (int r = 0; r < 4; r++) {
                int orow = wm * 64 + fm * 16 + lg * 4 + r;
                int o = o0 + orow;
                float bv = bias[o];
                float gv = 0.f, btv = 0.f;
                if constexpr (MODE == 2) { gv = gma[b * Cn + o]; btv = bta[b * Cn + o]; }
#pragma unroll
                for (int fn = 0; fn < 4; fn++) {
                    int lrow = wn * 64 + fn * 16 + li;
                    float v = acc[fm][fn][r] + bv;
                    if constexpr (MODE == 2) v = v * (1.f + gv) + btv;
                    ep[lrow * 130 + orow] = h2u((f16_t)v);
                }
            }
        }
        __syncthreads();
#pragma unroll
        for (int p = 0; p < 8; p++) {
            int idx = p * 256 + tid;       // 0..2047
            int lrow = idx >> 4;           // 0..127
            int c8 = (idx & 15) * 8;       // 0..120
            f16x8 hv;
#pragma unroll
            for (int u = 0; u < 8; u++) hv[u] = u2h(ep[lrow * 130 + c8 + u]);
            *(f16x8*)(out0 + bLC + (size_t)(l0 + lrow) * Cn + o0 + c8) = hv;
        }
    }
}

// ---- key_pool[b,l] = sum_c vsp_w[c]*mvn(style)[b,c,l] + vsp_b ----
__global__ __launch_bounds__(256) void keypool_kernel(const float* __restrict__ style,
                                                      const float* __restrict__ vsp_w,
                                                      const float* __restrict__ vsp_b,
                                                      const float* __restrict__ mean_s,
                                                      const float* __restrict__ rstd_s,
                                                      float* __restrict__ kp) {
    int b = blockIdx.y;
    int l = blockIdx.x * 256 + threadIdx.x;
    const size_t bCL = (size_t)b * Cn * Ln;
    float acc = 0.f;
    for (int c = 0; c < Cn; c++) {
        float v = style[bCL + (size_t)c * Ln + l];
        acc += vsp_w[c] * (v - mean_s[b * Cn + c]) * rstd_s[b * Cn + c];
    }
    kp[b * Ln + l] = acc + vsp_b[0];
}

// ---- softmax over L per b, in place ----
__global__ __launch_bounds__(1024) void softmax_kp_kernel(float* __restrict__ kp) {
    int b = blockIdx.x;
    float* p = kp + (size_t)b * Ln;
    int tid = threadIdx.x;
    float v[4];
    float m = -3e38f;
#pragma unroll
    for (int j = 0; j < 4; j++) { v[j] = p[tid + 1024 * j]; m = fmaxf(m, v[j]); }
    __shared__ float red[16];
    for (int off = 32; off; off >>= 1) m = fmaxf(m, __shfl_down(m, off));
    if ((tid & 63) == 0) red[tid >> 6] = m;
    __syncthreads();
    if (tid == 0) {
        float mm = red[0];
        for (int i = 1; i < 16; i++) mm = fmaxf(mm, red[i]);
        red[0] = mm;
    }
    __syncthreads();
    m = red[0];
    __syncthreads();
    float e[4]; float s = 0.f;
#pragma unroll
    for (int j = 0; j < 4; j++) { e[j] = __expf(v[j] - m); s += e[j]; }
    for (int off = 32; off; off >>= 1) s += __shfl_down(s, off);
    if ((tid & 63) == 0) red[tid >> 6] = s;
    __syncthreads();
    if (tid == 0) {
        float ss = 0.f;
        for (int i = 0; i < 16; i++) ss += red[i];
        red[0] = ss;
    }
    __syncthreads();
    float inv = 1.0f / red[0];
#pragma unroll
    for (int j = 0; j < 4; j++) p[tid + 1024 * j] = e[j] * inv;
}

// ---- gsv[b,c] = sum_l Vf[b,c,l]*w[b,l] ----
__global__ __launch_bounds__(256) void gsv_kernel(const f16_t* __restrict__ Vf,
                                                  const float* __restrict__ w,
                                                  float* __restrict__ gsv) {
    int c = blockIdx.x, b = blockIdx.y;
    int tid = threadIdx.x;
    const f16_t* vp = Vf + ((size_t)b * Cn + c) * Ln;
    const float* wp = w + (size_t)b * Ln;
    float acc = 0.f;
    for (int base = tid * 8; base < Ln; base += 2048) {
        f16x8 v = *(const f16x8*)(vp + base);
        float4 w0 = *(const float4*)(wp + base);
        float4 w1 = *(const float4*)(wp + base + 4);
        acc += (float)v[0] * w0.x + (float)v[1] * w0.y + (float)v[2] * w0.z + (float)v[3] * w0.w;
        acc += (float)v[4] * w1.x + (float)v[5] * w1.y + (float)v[6] * w1.z + (float)v[7] * w1.w;
    }
    for (int off = 32; off; off >>= 1) acc += __shfl_down(acc, off);
    __shared__ float red[4];
    if ((tid & 63) == 0) red[tid >> 6] = acc;
    __syncthreads();
    if (tid == 0) gsv[(size_t)b * Cn + c] = red[0] + red[1] + red[2] + red[3];
}

// ---- MLP stage 1 ----
__global__ __launch_bounds__(256) void mlp_hidden_kernel(const float* __restrict__ gsv,
                                                         const float* __restrict__ w1a, const float* __restrict__ b1a,
                                                         const float* __restrict__ w1b, const float* __restrict__ b1b,
                                                         float* __restrict__ h1, float* __restrict__ h2) {
    int idx = blockIdx.x * 256 + threadIdx.x;
    int b = idx / Cn, c = idx % Cn;
    float a1 = b1a[c], a2 = b1b[c];
    for (int k = 0; k < Cn; k++) {
        float g = gsv[b * Cn + k];
        a1 += w1a[(size_t)c * Cn + k] * g;
        a2 += w1b[(size_t)c * Cn + k] * g;
    }
    h1[idx] = fmaxf(a1, 0.f);
    h2[idx] = fmaxf(a2, 0.f);
}

// ---- MLP stage 2 ----
__global__ __launch_bounds__(256) void mlp_out_kernel(const float* __restrict__ h1, const float* __restrict__ h2,
                                                      const float* __restrict__ w2a, const float* __restrict__ b2a,
                                                      const float* __restrict__ w2b, const float* __restrict__ b2b,
                                                      float* __restrict__ gamma, float* __restrict__ beta) {
    int idx = blockIdx.x * 256 + threadIdx.x;
    int b = idx / Cn, c = idx % Cn;
    float a1 = b2a[c], a2 = b2b[c];
    for (int k = 0; k < Cn; k++) {
        a1 += w2a[(size_t)c * Cn + k] * h1[b * Cn + k];
        a2 += w2b[(size_t)c * Cn + k] * h2[b * Cn + k];
    }
    gamma[idx] = a1;
    beta[idx] = a2;
}

// ---- fp16 MFMA flash attention: BQ=32, BK=64, 4 waves.
//      Q in LDS (staged once); K fragments global->register 2-chunk ring
//      (per-wave key ownership, no LDS, no energy barriers);
//      V global->register 2-deep; 2 lgkm-only barriers per tile. ----
__global__ __launch_bounds__(256, 2) void flash_kernel(
    const f16_t* __restrict__ Qf, const f16_t* __restrict__ Kf,
    const f16_t* __restrict__ Vf, float* __restrict__ Ot) {
    const int b = blockIdx.y;
    const int q0 = blockIdx.x * 32;
    const int tid = threadIdx.x;
    const int lane = tid & 63;
    const int wn = tid >> 6;                 // 0..3: key group (energy) / c group (PV)
    const int lg = lane >> 4, li = lane & 15;

    __shared__ __align__(16) f16_t q_s[32 * 512];    // 32KB, pitch 1024B, swz (row&7)<<4
    __shared__ __align__(16) f16_t pb_s[32 * 64];    // 4KB, pitch 128B, swz (q&7)<<4
    __shared__ float smx[4][32];
    __shared__ float sml[4][32];

    const size_t qbase = ((size_t)b * Ln + q0) * Cn;
    const size_t kbase = (size_t)b * Ln * Cn;
    const size_t vbase = (size_t)b * Cn * Ln;

    // ---- stage Q via global_load_lds (pre-swizzled source, linear dest) ----
#pragma unroll
    for (int i = 0; i < 8; i++) {
        int idx = i * 256 + tid;
        int row = idx >> 6, slot = idx & 63;
        int sp = (slot & 56) | ((slot & 7) ^ (row & 7));
        gll16(Qf + qbase + (size_t)row * Cn + sp * 8, q_s + (size_t)idx * 8);
    }
    __syncthreads();

    const int key = wn * 16 + li;            // this wave's key row (energy)

    // K chunk -> registers: chunk g covers keys [this wave's 16] x 64 c
    // kreg ring of 2 chunks, statically indexed
    f16x8 kreg[2][2];
    auto loadK = [&](int g, int slot) {
        int ktA = (g >> 3) << 6;
        int cc = (g & 7) * 64;
        const f16_t* kp = Kf + kbase + (size_t)(ktA + key) * Cn + cc + lg * 8;
        kreg[slot][0] = *(const f16x8*)(kp);
        kreg[slot][1] = *(const f16x8*)(kp + 32);
    };
    loadK(0, 0);
    loadK(1, 1);

    f32x4 o[2][8];
#pragma unroll
    for (int m = 0; m < 2; m++)
#pragma unroll
        for (int j = 0; j < 8; j++) o[m][j] = (f32x4){0.f, 0.f, 0.f, 0.f};
    float m_run[2][4], l_run[2][4];
#pragma unroll
    for (int m = 0; m < 2; m++)
#pragma unroll
        for (int r = 0; r < 4; r++) { m_run[m][r] = -1e30f; l_run[m][r] = 0.f; }

    for (int tile = 0; tile < 64; tile++) {
        const int kt = tile * 64;
        f32x4 e[2];
#pragma unroll
        for (int m = 0; m < 2; m++) e[m] = (f32x4){0.f, 0.f, 0.f, 0.f};

        // ================= energy: 8 chunks, K from regs, no barriers =================
#pragma unroll
        for (int cs = 0; cs < 8; cs++) {
            const int slot = cs & 1;
            f16x8 k0 = kreg[slot][0], k1 = kreg[slot][1];
            {   // refill this slot with chunk cur+2 (wraps at end: harmless valid reads)
                int g2 = (tile * 8 + cs + 2) & 511;
                loadK(g2, slot);
            }
            f16x8 aq0[2], aq1[2];
#pragma unroll
            for (int m = 0; m < 2; m++) {
                int row = m * 16 + li;
                unsigned swz = (unsigned)((row & 7) << 4);
                aq0[m] = *(const f16x8*)((const char*)q_s + row * 1024 + ((cs * 128 + lg * 16) ^ swz));
                aq1[m] = *(const f16x8*)((const char*)q_s + row * 1024 + ((cs * 128 + 64 + lg * 16) ^ swz));
            }
            __builtin_amdgcn_s_setprio(1);
#pragma unroll
            for (int m = 0; m < 2; m++) {
                e[m] = mfma_f16(aq0[m], k0, e[m]);
                e[m] = mfma_f16(aq1[m], k1, e[m]);
            }
            __builtin_amdgcn_s_setprio(0);
        }

        // ---- issue V prefetch for PV steps 0,1 (softmax covers latency) ----
        f16x8 va[2], vb[2];
        {
            const f16_t* vp0 = Vf + vbase + (size_t)(wn * 16 + li) * Ln + kt + lg * 8;
            va[0] = *(const f16x8*)(vp0);
            vb[0] = *(const f16x8*)(vp0 + 32);
            const f16_t* vp1 = Vf + vbase + (size_t)((4 + wn) * 16 + li) * Ln + kt + lg * 8;
            va[1] = *(const f16x8*)(vp1);
            vb[1] = *(const f16x8*)(vp1 + 32);
        }

        // ================= online softmax (lgkm-only barriers) =================
        float tmax[2][4];
#pragma unroll
        for (int m = 0; m < 2; m++)
#pragma unroll
            for (int r = 0; r < 4; r++) tmax[m][r] = e[m][r];
#pragma unroll
        for (int d = 1; d < 16; d <<= 1)
#pragma unroll
            for (int m = 0; m < 2; m++)
#pragma unroll
                for (int r = 0; r < 4; r++) tmax[m][r] = fmaxf(tmax[m][r], __shfl_xor(tmax[m][r], d));
        if (li == 0) {
#pragma unroll
            for (int m = 0; m < 2; m++)
#pragma unroll
                for (int r = 0; r < 4; r++) smx[wn][m * 16 + lg * 4 + r] = tmax[m][r];
        }
        asm volatile("s_waitcnt lgkmcnt(0)\n\ts_barrier" ::: "memory");
        float scv[2][4];
        bool anyresc = false;
#pragma unroll
        for (int m = 0; m < 2; m++)
#pragma unroll
            for (int r = 0; r < 4; r++) {
                int row = m * 16 + lg * 4 + r;
                float tm = fmaxf(fmaxf(smx[0][row], smx[1][row]), fmaxf(smx[2][row], smx[3][row]));
                float mnew = fmaxf(m_run[m][r], tm);
                scv[m][r] = __expf(m_run[m][r] - mnew);
                anyresc |= (mnew > m_run[m][r]);
                m_run[m][r] = mnew;
            }
        float pv[2][4], rsum[2][4];
#pragma unroll
        for (int m = 0; m < 2; m++)
#pragma unroll
            for (int r = 0; r < 4; r++) {
                float pe = __expf(e[m][r] - m_run[m][r]);
                pv[m][r] = pe;
                rsum[m][r] = pe;
            }
#pragma unroll
        for (int d = 1; d < 16; d <<= 1)
#pragma unroll
            for (int m = 0; m < 2; m++)
#pragma unroll
                for (int r = 0; r < 4; r++) rsum[m][r] += __shfl_xor(rsum[m][r], d);
        if (li == 0) {
#pragma unroll
            for (int m = 0; m < 2; m++)
#pragma unroll
                for (int r = 0; r < 4; r++) sml[wn][m * 16 + lg * 4 + r] = rsum[m][r];
        }
        // write P fp16 to LDS (swizzled for b128 A-frag reads)
#pragma unroll
        for (int m = 0; m < 2; m++)
#pragma unroll
            for (int r = 0; r < 4; r++) {
                int qrow = m * 16 + lg * 4 + r;
                unsigned boff = (unsigned)(qrow * 128 + ((2 * key) ^ ((qrow & 7) << 4)));
                *(f16_t*)((char*)pb_s + boff) = (f16_t)pv[m][r];
            }
        // rescale O (skip when all scv == 1: exact identity)
        if (__any((int)anyresc)) {
#pragma unroll
            for (int m = 0; m < 2; m++)
#pragma unroll
                for (int j = 0; j < 8; j++)
#pragma unroll
                    for (int r = 0; r < 4; r++) o[m][j][r] *= scv[m][r];
        }
        asm volatile("s_waitcnt lgkmcnt(0)\n\ts_barrier" ::: "memory");
#pragma unroll
        for (int m = 0; m < 2; m++)
#pragma unroll
            for (int r = 0; r < 4; r++) {
                int row = m * 16 + lg * 4 + r;
                l_run[m][r] = l_run[m][r] * scv[m][r] + sml[0][row] + sml[1][row] + sml[2][row] + sml[3][row];
            }

        // ================= PV: P from LDS (b128), V from L2, 2-deep prefetch ====
        f16x8 pa[2][2];
#pragma unroll
        for (int m = 0; m < 2; m++)
#pragma unroll
            for (int k2 = 0; k2 < 2; k2++) {
                int qrow = m * 16 + li;
                pa[m][k2] = *(const f16x8*)((const char*)pb_s + qrow * 128 +
                              ((k2 * 64 + lg * 16) ^ ((qrow & 7) << 4)));
            }
#pragma unroll
        for (int n = 0; n < 8; n++) {
            const int slot = n & 1;
            f16x8 c0 = va[slot], c1 = vb[slot];
            if (n + 2 < 8) {
                int cg = (n + 2) * 4 + wn;
                const f16_t* vp = Vf + vbase + (size_t)(cg * 16 + li) * Ln + kt + lg * 8;
                va[slot] = *(const f16x8*)(vp);
                vb[slot] = *(const f16x8*)(vp + 32);
            }
            __builtin_amdgcn_s_setprio(1);
#pragma unroll
            for (int m = 0; m < 2; m++) {
                o[m][n] = mfma_f16(pa[m][0], c0, o[m][n]);
                o[m][n] = mfma_f16(pa[m][1], c1, o[m][n]);
            }
            __builtin_amdgcn_s_setprio(0);
        }
    }

    // ================= epilogue: O^T -> d_out [B][C][L], float4 along L =================
#pragma unroll
    for (int m = 0; m < 2; m++)
#pragma unroll
        for (int r = 0; r < 4; r++) l_run[m][r] = 1.f / l_run[m][r];
#pragma unroll
    for (int m = 0; m < 2; m++)
#pragma unroll
        for (int n = 0; n < 8; n++) {
            int c = (n * 4 + wn) * 16 + li;
            int qg = q0 + m * 16 + lg * 4;
            float4 ov;
            ov.x = o[m][n][0] * l_run[m][0];
            ov.y = o[m][n][1] * l_run[m][1];
            ov.z = o[m][n][2] * l_run[m][2];
            ov.w = o[m][n][3] * l_run[m][3];
            *(float4*)(Ot + vbase + (size_t)c * Ln + qg) = ov;
        }
}

// ---- final: out[b,c,l] = mvn(content)[b,c,l] + out[b,c,l]  (in place) ----
__global__ __launch_bounds__(256) void final_kernel(const float* __restrict__ content,
                                                    const float* __restrict__ mean_c,
                                                    const float* __restrict__ rstd_c,
                                                    float* __restrict__ out) {
    size_t gid = (size_t)blockIdx.x * 256 + threadIdx.x;
    size_t linear = gid * 4;
    int ch = (int)(linear / Ln);
    float m = mean_c[ch], rs = rstd_c[ch];
    float4 cv = *(const float4*)(content + linear);
    float4 ov = *(const float4*)(out + linear);
    ov.x += (cv.x - m) * rs;
    ov.y += (cv.y - m) * rs;
    ov.z += (cv.z - m) * rs;
    ov.w += (cv.w - m) * rs;
    *(float4*)(out + linear) = ov;
}

extern "C" void kernel_launch(void* const* d_in, const int* in_sizes, int n_in,
                              void* d_out, int out_size, void* d_ws, size_t ws_size,
                              hipStream_t stream) {
    const float* content = (const float*)d_in[0];
    const float* style   = (const float*)d_in[1];
    const float* v_w   = (const float*)d_in[2];
    const float* v_b   = (const float*)d_in[3];
    const float* vsp_w = (const float*)d_in[4];
    const float* vsp_b = (const float*)d_in[5];
    const float* k_w   = (const float*)d_in[6];
    const float* k_b   = (const float*)d_in[7];
    const float* qg_w  = (const float*)d_in[8];
    const float* qg_b  = (const float*)d_in[9];
    const float* g1_w1 = (const float*)d_in[10];
    const float* g1_b1 = (const float*)d_in[11];
    const float* g1_w2 = (const float*)d_in[12];
    const float* g1_b2 = (const float*)d_in[13];
    const float* g2_w1 = (const float*)d_in[14];
    const float* g2_b1 = (const float*)d_in[15];
    const float* g2_w2 = (const float*)d_in[16];
    const float* g2_b2 = (const float*)d_in[17];

    f16_t* wsh = (f16_t*)d_ws;
    f16_t* Qf = wsh;
    f16_t* Kf = wsh + NQK;
    f16_t* Vf = wsh + 2 * NQK;
    bf16_t* wsp = (bf16_t*)(wsh + 3 * NQK);
    bf16_t* Wv_hi = wsp;            bf16_t* Wv_lo = wsp + CC;
    bf16_t* Wk_hi = wsp + 2 * CC;   bf16_t* Wk_lo = wsp + 3 * CC;
    bf16_t* Wq_hi = wsp + 4 * CC;   bf16_t* Wq_lo = wsp + 5 * CC;

    float* wsf = (float*)(wsp + 6 * CC);
    float* mean_s = wsf + FOFF_MEANS;
    float* rstd_s = wsf + FOFF_RSTDS;
    float* mean_c = wsf + FOFF_MEANC;
    float* rstd_c = wsf + FOFF_RSTDC;
    float* kp     = wsf + FOFF_KP;
    float* gsv    = wsf + FOFF_GSV;
    float* h1     = wsf + FOFF_H1;
    float* h2     = wsf + FOFF_H2;
    float* gamma  = wsf + FOFF_GAMMA;
    float* beta   = wsf + FOFF_BETA;

    // d_out doubles as scratch for transposed input splits
    bf16_t* XThi = (bf16_t*)d_out;
    bf16_t* XTlo = XThi + NQK;
    float* outF  = (float*)d_out;

    // 1) stats
    stats_kernel<<<dim3(Bn * Cn), 256, 0, stream>>>(style, mean_s, rstd_s);
    stats_kernel<<<dim3(Bn * Cn), 256, 0, stream>>>(content, mean_c, rstd_c);

    // 2) weight splits + style transpose-split (into d_out)
    split_w_kernel<<<dim3(CC / 2048, 3), 256, 0, stream>>>(v_w, k_w, qg_w, wsp);
    split_xt_kernel<false><<<dim3(Ln / 32, Cn / 32, Bn), 256, 0, stream>>>(style, nullptr, nullptr, XThi, XTlo);

    // 3) V conv -> fp16 [B][C][L]
    dim3 cgrid(Ln / 128, Cn / 128, Bn);
    conv_mfma_kernel<0><<<cgrid, 256, 0, stream>>>(Wv_hi, Wv_lo, XThi, XTlo, v_b, nullptr, nullptr, Vf);

    // 4) key_pool + softmax + gsv + MLPs -> gamma, beta
    keypool_kernel<<<dim3(Ln / 256, Bn), 256, 0, stream>>>(style, vsp_w, vsp_b, mean_s, rstd_s, kp);
    softmax_kp_kernel<<<dim3(Bn), 1024, 0, stream>>>(kp);
    gsv_kernel<<<dim3(Cn, Bn), 256, 0, stream>>>(Vf, kp, gsv);
    mlp_hidden_kernel<<<dim3(Bn * Cn / 256), 256, 0, stream>>>(gsv, g1_w1, g1_b1, g2_w1, g2_b1, h1, h2);
    mlp_out_kernel<<<dim3(Bn * Cn / 256), 256, 0, stream>>>(h1, h2, g1_w2, g1_b2, g2_w2, g2_b2, gamma, beta);

    // 5) K conv -> fp16 [B][L][C]
    conv_mfma_kernel<1><<<cgrid, 256, 0, stream>>>(Wk_hi, Wk_lo, XThi, XTlo, k_b, nullptr, nullptr, Kf);

    // 6) content mvn transpose-split (overwrites style split), then Q conv (gamma/beta fused)
    split_xt_kernel<true><<<dim3(Ln / 32, Cn / 32, Bn), 256, 0, stream>>>(content, mean_c, rstd_c, XThi, XTlo);
    conv_mfma_kernel<2><<<cgrid, 256, 0, stream>>>(Wq_hi, Wq_lo, XThi, XTlo, qg_b, gamma, beta, Qf);

    // 7) flash attention -> O^T into d_out
    flash_kernel<<<dim3(Ln / 32, Bn), 256, 0, stream>>>(Qf, Kf, Vf, outF);

    // 8) final: add mvn(content) in place
    final_kernel<<<dim3((Bn * Cn * (Ln / 4)) / 256), 256, 0, stream>>>(content, mean_c, rstd_c, outF);
}